// Round 3
// baseline (271.097 us; speedup 1.0000x reference)
//
#include <hip/hip_runtime.h>

// CRF NLL on MI355X, round 5: resubmit of round 4 (infra failure, no data).
// 256 threads = 4 waves = 1 wave/SIMD.
// Latency-bound sequential scan (1 block/batch-elem, ~512 dependent steps).
// Round-3 post-mortem: per-step ~764cy vs ~360cy bottom-up model; gap
// attributed to 2-waves/SIMD round-robin + 8-wave barrier jitter. This
// round halves the wave count: 32 teams x 8 subs, each team owns 4 columns
// (j0=4jp..+3). Per-lane FMA work doubles (+~32cy issue on idle SIMDs);
// LDS reads unchanged (4x ds_read_b128, conflict-free kkA swizzle); writer
// emits one ds_write_b128 (32 lanes -> 32 distinct banks). DPP team-reduce
// and deferred every-4-step rescale kept from round 3.

#define BB   128
#define TT   512
#define CC   128
#define NTHR 256
#define PF   4

typedef float v2f __attribute__((ext_vector_type(2)));

__device__ __forceinline__ void bar_nodrain() {
    // LDS-visibility barrier that does NOT drain vmcnt (global prefetch stays
    // in flight). "memory" clobber stops compiler reordering across it.
    asm volatile("s_waitcnt lgkmcnt(0)\n\ts_barrier" ::: "memory");
}

template<int CTRL>
__device__ __forceinline__ float dpp_xadd(float x) {
    const int y = __builtin_amdgcn_update_dpp(0, __float_as_int(x), CTRL, 0xF, 0xF, true);
    return x + __int_as_float(y);
}

// Sum across each aligned group of 8 lanes (team) at VALU speed.
__device__ __forceinline__ float red8(float x) {
    x = dpp_xadd<0xB1>(x);    // quad_perm(1,0,3,2): + lane^1
    x = dpp_xadd<0x4E>(x);    // quad_perm(2,3,0,1): + lane^2
    x = dpp_xadd<0x141>(x);   // row_half_mirror:    + lane^4 within each 8
    return x;
}

__global__ __launch_bounds__(NTHR) void crf_fused(
    const float* __restrict__ feats,
    const int*   __restrict__ mask,
    const int*   __restrict__ tags,
    const float* __restrict__ trans,
    float*       __restrict__ acc)   // acc[0] += forward, acc[1] += gold score
{
    const int b   = blockIdx.x;
    const int tid = threadIdx.x;
    const int jp  = tid >> 3;        // team: columns 4jp..4jp+3
    const int sub = tid & 7;         // 16-row i-slice
    const int j0  = jp * 4;
    const int wid = tid >> 6;

    __shared__ __align__(16) float buf[2][CC];  // double-buffered u vector
    __shared__ float wred[4];

    // ---- sequence length (contiguous prefix mask; 256 threads span T in 2) ----
    const int base = b * TT;
    const int m0 = mask[base + tid];
    const int m1 = mask[base + tid + 256];
    const int len = __syncthreads_count(m0) + __syncthreads_count(m1);

    // ---- gold-path score (once; off the scan's critical path) ----
    {
        float sc = 0.0f;
        if (m0) {                        // position t = tid (0..255)
            const int tg = tags[base + tid];
            sc += feats[((size_t)(base + tid)) * CC + tg];
            sc += (tid == 0) ? trans[(CC - 2) * CC + tg]
                             : trans[tags[base + tid - 1] * CC + tg];
            const int nm = mask[base + tid + 1];   // tid+1 <= 256 < TT
            if (!nm) sc += trans[tg * CC + (CC - 1)];
        }
        if (m1) {                        // position t = tid + 256 (256..511)
            const int t2 = tid + 256;
            const int tg = tags[base + t2];
            sc += feats[((size_t)(base + t2)) * CC + tg];
            sc += trans[tags[base + t2 - 1] * CC + tg];
            const int nm = (t2 == TT - 1) ? 0 : mask[base + t2 + 1];
            if (!nm) sc += trans[tg * CC + (CC - 1)];
        }
        #pragma unroll
        for (int o = 1; o <= 32; o <<= 1) sc += __shfl_xor(sc, o);
        if ((tid & 63) == 0) wred[wid] = sc;
        __syncthreads();
        if (tid == 0) {
            float s = 0.0f;
            #pragma unroll
            for (int k = 0; k < 4; ++k) s += wred[k];
            atomicAdd(&acc[1], s);
        }
        // wred re-used only after the post-loop __syncthreads().
    }

    // ---- E fragments: 16 rows x 4 cols per lane, chunk order swizzled so the
    //      wave's 8 distinct 16B buf-chunks hit 8 distinct bank quads ----
    const int s2 = sub >> 1;
    int kkA[4];
    v2f Ev[4][8];                        // [col][row-pair], kkA chunk order
    #pragma unroll
    for (int k = 0; k < 4; ++k) {
        const int kk = (k + s2) & 3;
        kkA[k] = kk;
        const int r = sub * 16 + kk * 4;
        #pragma unroll
        for (int m = 0; m < 2; ++m) {
            const int r0 = r + 2 * m;
            const float4 ta = *(const float4*)&trans[(size_t)(r0    ) * CC + j0];
            const float4 tb = *(const float4*)&trans[(size_t)(r0 + 1) * CC + j0];
            const float* tap = (const float*)&ta;
            const float* tbp = (const float*)&tb;
            #pragma unroll
            for (int c = 0; c < 4; ++c) {
                v2f e;
                e.x = __expf(tap[c]);
                e.y = __expf(tbp[c]);
                Ev[c][2 * k + m] = e;
            }
        }
    }
    // terminal transition-to-STOP factors for this team's 4 columns
    float Es[4];
    #pragma unroll
    for (int c = 0; c < 4; ++c)
        Es[c] = __expf(trans[(size_t)(j0 + c) * CC + (CC - 1)]);

    // ---- init: u_0 = 1 at START(126), 0 elsewhere ----
    if (tid < CC) buf[0][tid] = (tid == CC - 2) ? 1.0f : 0.0f;

    // ---- feats prefetch (PF deep, rotating registers, float4/lane) ----
    const float* fb = feats + (size_t)b * TT * CC;
    float4 fx[PF];
    #pragma unroll
    for (int k = 0; k < PF; ++k)
        fx[k] = *(const float4*)&fb[(size_t)k * CC + j0];

    const float* pb0 = &buf[0][sub * 16];
    const float* pb1 = &buf[1][sub * 16];

    float S = 0.0f;                          // sum of applied log(c)
    const int lenUp = (len + 3) & ~3;

    for (int tc = 0; tc < lenUp; tc += 4) {
        #pragma unroll
        for (int k = 0; k < 4; ++k) {
            const int t   = tc + k;
            const int par = k & 1;           // == t & 1
            bar_nodrain();                   // buf[par] now visible
            const float4* q = (const float4*)(par ? pb1 : pb0);
            float cval = 1.0f;
            if (k == 3) cval = buf[1][0];    // current u_t[0] (par==1); broadcast

            v2f accA[4] = {{0.f, 0.f}, {0.f, 0.f}, {0.f, 0.f}, {0.f, 0.f}};
            v2f accB[4] = {{0.f, 0.f}, {0.f, 0.f}, {0.f, 0.f}, {0.f, 0.f}};
            #pragma unroll
            for (int kq = 0; kq < 4; ++kq) {
                const float4 P = q[kkA[kq]];
                v2f P01; P01.x = P.x; P01.y = P.y;
                v2f P23; P23.x = P.z; P23.y = P.w;
                #pragma unroll
                for (int c = 0; c < 4; ++c) {
                    accA[c] = __builtin_elementwise_fma(Ev[c][2 * kq],     P01, accA[c]);
                    accB[c] = __builtin_elementwise_fma(Ev[c][2 * kq + 1], P23, accB[c]);
                }
            }
            float s[4];
            #pragma unroll
            for (int c = 0; c < 4; ++c) {
                const v2f ab = accA[c] + accB[c];
                s[c] = red8(ab.x + ab.y);
            }

            // exps stay inside step k: keeps the global prefetch a full
            // PF=4 steps ahead of consumption.
            const float* fxp = (const float*)&fx[k];
            float v[4];
            if (k == 3) {
                const float rinv = __builtin_amdgcn_rcpf(cval);
                #pragma unroll
                for (int c = 0; c < 4; ++c) v[c] = __expf(fxp[c]) * s[c] * rinv;
            } else {
                #pragma unroll
                for (int c = 0; c < 4; ++c) v[c] = __expf(fxp[c]) * s[c];
            }

            // prefetch feats for step t+PF (clamped; identical work each call)
            int tn = t + PF;
            tn = (tn < TT) ? tn : (TT - 1);
            fx[k] = *(const float4*)&fb[(size_t)tn * CC + j0];

            if (t < len) {                   // uniform branch
                if (k == 3) S += __logf(cval);  // record exactly what was divided
                if (sub == 0) {
                    float4 w4;
                    w4.x = v[0]; w4.y = v[1]; w4.z = v[2]; w4.w = v[3];
                    *(float4*)&buf[par ^ 1][j0] = w4;   // 32 lanes -> 32 banks
                }
            }
            // steps t >= len: no writes -> state frozen (padding is a no-op)
        }
    }

    // ---- terminal: log(sum_j u_len[j] * exp(trans[j][STOP])) + S ----
    __syncthreads();                         // full barrier: buf/wred safe
    const float4 uu = *(const float4*)&buf[len & 1][j0];
    float z = 0.0f;
    if (sub == 0)
        z = uu.x * Es[0] + uu.y * Es[1] + uu.z * Es[2] + uu.w * Es[3];
    #pragma unroll
    for (int o = 1; o <= 32; o <<= 1) z += __shfl_xor(z, o);
    if ((tid & 63) == 0) wred[wid] = z;
    __syncthreads();
    if (tid == 0) {
        float s = 0.0f;
        #pragma unroll
        for (int k = 0; k < 4; ++k) s += wred[k];
        atomicAdd(&acc[0], __logf(s) + S);
    }
}

__global__ void crf_final(const float* __restrict__ acc, float* __restrict__ out)
{
    out[0] = (acc[0] - acc[1]) * (1.0f / (float)BB);
}

extern "C" void kernel_launch(void* const* d_in, const int* in_sizes, int n_in,
                              void* d_out, int out_size, void* d_ws, size_t ws_size,
                              hipStream_t stream)
{
    const float* feats = (const float*)d_in[0];
    const int*   mask  = (const int*)d_in[1];
    const int*   tags  = (const int*)d_in[2];
    const float* trans = (const float*)d_in[3];
    float* out = (float*)d_out;
    float* acc = (float*)d_ws;

    hipMemsetAsync(acc, 0, 2 * sizeof(float), stream);
    crf_fused<<<BB, NTHR, 0, stream>>>(feats, mask, tags, trans, acc);
    crf_final<<<1, 1, 0, stream>>>(acc, out);
}

// Round 4
// 213.037 us; speedup vs baseline: 1.2725x; 1.2725x over previous
//
#include <hip/hip_runtime.h>

// CRF NLL on MI355X, round 6: BIDIRECTIONAL scan — halve sequential depth.
// Z = sum_i a_M[i]*b_M[i]: forward scan (a, from t=0) and backward scan
// (b, from t=len) run CONCURRENTLY in one block, interleaved per step;
// dependent-step count drops 512 -> ceil(len/2). Step latency is mostly
// fixed overhead (barrier + LDS round trip), so doubling per-step work
// costs ~1.3x, not 2x  -> net ~1.5x predicted.
// Geometry per stream = round-3 optimum: 512 thr, 64 teams x 8 subs,
// team jp owns cols j0=2jp,j0+1; sub owns a 16-row slice. DPP team-reduce,
// deferred every-4-step rescale (separate SF/SB), PF=4 feats prefetch per
// stream. Backward premultiplies f into the LDS vector at the WRITER
// (writer owns exactly those columns); the LAST backward step skips the
// premultiply so the junction counts each feat exactly once.

#define BB   128
#define TT   512
#define CC   128
#define NTHR 512
#define PF   4

typedef float v2f __attribute__((ext_vector_type(2)));

__device__ __forceinline__ void bar_nodrain() {
    // LDS-visibility barrier that does NOT drain vmcnt (global prefetch stays
    // in flight). "memory" clobber stops compiler reordering across it.
    asm volatile("s_waitcnt lgkmcnt(0)\n\ts_barrier" ::: "memory");
}

template<int CTRL>
__device__ __forceinline__ float dpp_xadd(float x) {
    const int y = __builtin_amdgcn_update_dpp(0, __float_as_int(x), CTRL, 0xF, 0xF, true);
    return x + __int_as_float(y);
}

// Sum across each aligned group of 8 lanes (team) at VALU speed.
__device__ __forceinline__ float red8(float x) {
    x = dpp_xadd<0xB1>(x);    // quad_perm(1,0,3,2): + lane^1
    x = dpp_xadd<0x4E>(x);    // quad_perm(2,3,0,1): + lane^2
    x = dpp_xadd<0x141>(x);   // row_half_mirror:    + lane^4 within each 8
    return x;
}

__global__ __launch_bounds__(NTHR) void crf_fused(
    const float* __restrict__ feats,
    const int*   __restrict__ mask,
    const int*   __restrict__ tags,
    const float* __restrict__ trans,
    float*       __restrict__ acc)   // acc[0] += forward, acc[1] += gold score
{
    const int b   = blockIdx.x;
    const int tid = threadIdx.x;
    const int jp  = tid >> 3;        // team: columns 2jp, 2jp+1
    const int sub = tid & 7;         // 16-row slice of the reduction axis
    const int j0  = jp * 2;
    const int j1  = j0 + 1;
    const int wid = tid >> 6;

    __shared__ __align__(16) float buf_a[2][CC];  // fwd vector (double-buffered)
    __shared__ __align__(16) float buf_c[2][CC];  // bwd vector (premultiplied)
    __shared__ float wred[8];

    // ---- sequence length (contiguous prefix mask; tid spans T exactly) ----
    const int myM = mask[b * TT + tid];
    const int len = __syncthreads_count(myM);

    // ---- gold-path score (once; off the scan's critical path) ----
    {
        float sc = 0.0f;
        if (myM) {
            const int tg = tags[b * TT + tid];
            sc += feats[((size_t)(b * TT + tid)) * CC + tg];
            sc += (tid == 0) ? trans[(CC - 2) * CC + tg]
                             : trans[tags[b * TT + tid - 1] * CC + tg];
            const int nm = (tid == TT - 1) ? 0 : mask[b * TT + tid + 1];
            if (!nm) sc += trans[tg * CC + (CC - 1)];
        }
        #pragma unroll
        for (int o = 1; o <= 32; o <<= 1) sc += __shfl_xor(sc, o);
        if ((tid & 63) == 0) wred[wid] = sc;
        __syncthreads();
        if (tid == 0) {
            float s = 0.0f;
            #pragma unroll
            for (int k = 0; k < 8; ++k) s += wred[k];
            atomicAdd(&acc[1], s);
        }
        // wred re-used only after the post-loop __syncthreads().
    }

    // ---- E fragments (fwd: cols j0,j1 over a 16-row slice), chunk order
    //      swizzled so each wave's 8 distinct 16B chunks hit 8 bank quads ----
    const int s2 = sub >> 1;
    int kkA[4];
    v2f E0v[8], E1v[8];              // fwd: E[r][j0], E[r][j1], row-pairs
    v2f T0v[8], T1v[8];              // bwd: E[j0][r], E[j1][r], col-pairs
    #pragma unroll
    for (int k = 0; k < 4; ++k) {
        const int kk = (k + s2) & 3;
        kkA[k] = kk;
        const int r = sub * 16 + kk * 4;
        #pragma unroll
        for (int m = 0; m < 2; ++m) {
            const int r0 = r + 2 * m;
            const float2 ta = *(const float2*)&trans[(size_t)(r0    ) * CC + j0];
            const float2 tb = *(const float2*)&trans[(size_t)(r0 + 1) * CC + j0];
            v2f e0, e1;
            e0.x = __expf(ta.x); e0.y = __expf(tb.x);
            e1.x = __expf(ta.y); e1.y = __expf(tb.y);
            E0v[2 * k + m] = e0;
            E1v[2 * k + m] = e1;
        }
        // transposed fragments: rows j0/j1 of trans, 4 consecutive cols r..r+3
        const float4 u0 = *(const float4*)&trans[(size_t)j0 * CC + r];
        const float4 u1 = *(const float4*)&trans[(size_t)j1 * CC + r];
        v2f t00; t00.x = __expf(u0.x); t00.y = __expf(u0.y);
        v2f t01; t01.x = __expf(u0.z); t01.y = __expf(u0.w);
        v2f t10; t10.x = __expf(u1.x); t10.y = __expf(u1.y);
        v2f t11; t11.x = __expf(u1.z); t11.y = __expf(u1.w);
        T0v[2 * k]     = t00;  T0v[2 * k + 1] = t01;
        T1v[2 * k]     = t10;  T1v[2 * k + 1] = t11;
    }

    const float* fb = feats + (size_t)b * TT * CC;

    // ---- init: a_0 = onehot(START); c_init[j] = exp(trans[j][STOP]) * f_{len-1}[j]
    if (tid < CC) {
        buf_a[0][tid] = (tid == CC - 2) ? 1.0f : 0.0f;
        const float es = __expf(trans[(size_t)tid * CC + (CC - 1)]);
        buf_c[0][tid] = es * __expf(fb[(size_t)(len - 1) * CC + tid]);
    }

    // ---- feats prefetch: fwd walks t up from 0; bwd walks t down from len-2 ----
    float2 fxF[PF], fxB[PF];
    #pragma unroll
    for (int k = 0; k < PF; ++k) {
        fxF[k] = *(const float2*)&fb[(size_t)k * CC + j0];
        int tg = len - 2 - k; tg = (tg > 0) ? tg : 0;
        fxB[k] = *(const float2*)&fb[(size_t)tg * CC + j0];
    }

    const float* pa0 = &buf_a[0][sub * 16];
    const float* pa1 = &buf_a[1][sub * 16];
    const float* pc0 = &buf_c[0][sub * 16];
    const float* pc1 = &buf_c[1][sub * 16];

    const int M   = len >> 1;        // fwd steps; bwd steps nB = len - M >= 1
    const int nB  = len - M;
    const int nUp = (nB + 3) & ~3;

    float SF = 0.0f, SB = 0.0f;      // per-stream sums of applied log(c)

    for (int tc = 0; tc < nUp; tc += 4) {
        #pragma unroll
        for (int k = 0; k < 4; ++k) {
            const int it  = tc + k;
            const int par = k & 1;       // == it & 1
            bar_nodrain();               // buf_a[par], buf_c[par] now visible
            const float4* qf = (const float4*)(par ? pa1 : pa0);
            const float4* qb = (const float4*)(par ? pc1 : pc0);
            float cF = 1.0f, cB = 1.0f;
            if (k == 3) { cF = buf_a[1][0]; cB = buf_c[1][0]; }  // broadcast reads

            v2f fa0 = {0.f,0.f}, fa1 = {0.f,0.f}, fb0 = {0.f,0.f}, fb1 = {0.f,0.f};
            v2f ga0 = {0.f,0.f}, ga1 = {0.f,0.f}, gb0 = {0.f,0.f}, gb1 = {0.f,0.f};
            #pragma unroll
            for (int kq = 0; kq < 4; ++kq) {
                const float4 P = qf[kkA[kq]];
                const float4 Q = qb[kkA[kq]];
                v2f P01; P01.x = P.x; P01.y = P.y;
                v2f P23; P23.x = P.z; P23.y = P.w;
                v2f Q01; Q01.x = Q.x; Q01.y = Q.y;
                v2f Q23; Q23.x = Q.z; Q23.y = Q.w;
                fa0 = __builtin_elementwise_fma(E0v[2 * kq],     P01, fa0);
                fa1 = __builtin_elementwise_fma(E0v[2 * kq + 1], P23, fa1);
                fb0 = __builtin_elementwise_fma(E1v[2 * kq],     P01, fb0);
                fb1 = __builtin_elementwise_fma(E1v[2 * kq + 1], P23, fb1);
                ga0 = __builtin_elementwise_fma(T0v[2 * kq],     Q01, ga0);
                ga1 = __builtin_elementwise_fma(T0v[2 * kq + 1], Q23, ga1);
                gb0 = __builtin_elementwise_fma(T1v[2 * kq],     Q01, gb0);
                gb1 = __builtin_elementwise_fma(T1v[2 * kq + 1], Q23, gb1);
            }
            fa0 += fa1; fb0 += fb1; ga0 += ga1; gb0 += gb1;
            float s0 = red8(fa0.x + fa0.y);
            float s1 = red8(fb0.x + fb0.y);
            float t0 = red8(ga0.x + ga0.y);
            float t1 = red8(gb0.x + gb0.y);

            // fwd emission factor (exps stay inside step k: keeps global
            // prefetch a full PF=4 steps ahead of consumption)
            const float e0f = __expf(fxF[k].x);
            const float e1f = __expf(fxF[k].y);
            // bwd premultiplier f_{len-2-it}[j0..j1]; LAST bwd step writes raw
            const bool lastB = (it == nB - 1);
            const float m0 = lastB ? 1.0f : __expf(fxB[k].x);
            const float m1 = lastB ? 1.0f : __expf(fxB[k].y);

            float v0, v1, w0, w1;
            if (k == 3) {
                const float rF = __builtin_amdgcn_rcpf(cF);
                const float rB = __builtin_amdgcn_rcpf(cB);
                v0 = e0f * s0 * rF;  v1 = e1f * s1 * rF;
                w0 = m0  * t0 * rB;  w1 = m1  * t1 * rB;
            } else {
                v0 = e0f * s0;  v1 = e1f * s1;
                w0 = m0  * t0;  w1 = m1  * t1;
            }

            // prefetch feats for step it+PF on both streams (clamped)
            int tnF = it + PF;            tnF = (tnF < TT) ? tnF : (TT - 1);
            int tnB = len - 2 - (it + PF); tnB = (tnB > 0) ? tnB : 0;
            fxF[k] = *(const float2*)&fb[(size_t)tnF * CC + j0];
            fxB[k] = *(const float2*)&fb[(size_t)tnB * CC + j0];

            if (it < M) {                 // fwd active (uniform branch)
                if (k == 3) SF += __logf(cF);
                if (sub == 0) {
                    float2 w2; w2.x = v0; w2.y = v1;
                    *(float2*)&buf_a[par ^ 1][j0] = w2;
                }
            }
            if (it < nB) {                // bwd active (uniform branch)
                if (k == 3) SB += __logf(cB);
                if (sub == 0) {
                    float2 w2; w2.x = w0; w2.y = w1;
                    *(float2*)&buf_c[par ^ 1][j0] = w2;
                }
            }
            // frozen steps: no writes, no S updates -> stale/NaN temporaries
            // are discarded; state and bookkeeping stay exact.
        }
    }

    // ---- junction: logZ = log(sum_i a_M[i] * b_M[i]) + SF + SB ----
    __syncthreads();                     // full barrier: buf/wred safe
    const float2 aM = *(const float2*)&buf_a[M  & 1][j0];
    const float2 bM = *(const float2*)&buf_c[nB & 1][j0];
    float z = (sub == 0) ? (aM.x * bM.x + aM.y * bM.y) : 0.0f;
    #pragma unroll
    for (int o = 1; o <= 32; o <<= 1) z += __shfl_xor(z, o);
    if ((tid & 63) == 0) wred[wid] = z;
    __syncthreads();
    if (tid == 0) {
        float s = 0.0f;
        #pragma unroll
        for (int k = 0; k < 8; ++k) s += wred[k];
        atomicAdd(&acc[0], __logf(s) + SF + SB);
    }
}

__global__ void crf_final(const float* __restrict__ acc, float* __restrict__ out)
{
    out[0] = (acc[0] - acc[1]) * (1.0f / (float)BB);
}

extern "C" void kernel_launch(void* const* d_in, const int* in_sizes, int n_in,
                              void* d_out, int out_size, void* d_ws, size_t ws_size,
                              hipStream_t stream)
{
    const float* feats = (const float*)d_in[0];
    const int*   mask  = (const int*)d_in[1];
    const int*   tags  = (const int*)d_in[2];
    const float* trans = (const float*)d_in[3];
    float* out = (float*)d_out;
    float* acc = (float*)d_ws;

    hipMemsetAsync(acc, 0, 2 * sizeof(float), stream);
    crf_fused<<<BB, NTHR, 0, stream>>>(feats, mask, tags, trans, acc);
    crf_final<<<1, 1, 0, stream>>>(acc, out);
}

// Round 5
// 166.768 us; speedup vs baseline: 1.6256x; 1.2774x over previous
//
#include <hip/hip_runtime.h>

// CRF NLL on MI355X, round 7: bidirectional scan SPLIT ACROSS BLOCKS.
// Round-6 post-mortem: step latency ~= 215cy fixed + 550cy per stream; the
// two concurrent streams per block doubled the serial chain. Fix: grid=256
// (2 blocks per batch elem, one fwd one bwd) on 256 CUs — each block runs
// the lean round-3 single-stream step (~764cy) for only ~len/2 steps.
// Junction Z = sum_i aM[i]*bM[i] done by a tiny epilogue kernel reading the
// per-block result vectors from workspace (~160 KB of d_ws).
// Kept from prior rounds: 512 thr = 64 teams x 8 subs (2 cols/team, 16-row
// slice/sub), DPP team-reduce, deferred every-4-step rescale, PF=4 feats
// prefetch, conflict-free kkA chunk swizzle, no-drain barrier.

#define BB   128
#define TT   512
#define CC   128
#define NTHR 512
#define PF   4
#define WS_STRIDE 320   // floats/batch: [0:128) aM, [128:256) bM, [256] SF, [257] SB
// workspace bytes needed: (16 + BB*WS_STRIDE)*4 ~= 160 KB

typedef float v2f __attribute__((ext_vector_type(2)));

__device__ __forceinline__ void bar_nodrain() {
    // LDS-visibility barrier that does NOT drain vmcnt (global prefetch stays
    // in flight). "memory" clobber stops compiler reordering across it.
    asm volatile("s_waitcnt lgkmcnt(0)\n\ts_barrier" ::: "memory");
}

template<int CTRL>
__device__ __forceinline__ float dpp_xadd(float x) {
    const int y = __builtin_amdgcn_update_dpp(0, __float_as_int(x), CTRL, 0xF, 0xF, true);
    return x + __int_as_float(y);
}

// Sum across each aligned group of 8 lanes (team) at VALU speed.
__device__ __forceinline__ float red8(float x) {
    x = dpp_xadd<0xB1>(x);    // quad_perm(1,0,3,2): + lane^1
    x = dpp_xadd<0x4E>(x);    // quad_perm(2,3,0,1): + lane^2
    x = dpp_xadd<0x141>(x);   // row_half_mirror:    + lane^4 within each 8
    return x;
}

__global__ __launch_bounds__(NTHR) void crf_scan(
    const float* __restrict__ feats,
    const int*   __restrict__ mask,
    const int*   __restrict__ tags,
    const float* __restrict__ trans,
    float*       __restrict__ ws)    // ws[0]=fwd acc, ws[1]=gold acc, +16: vectors
{
    const int bb  = blockIdx.x >> 1;
    const int dir = blockIdx.x & 1;  // 0 = forward scan, 1 = backward scan
    const int tid = threadIdx.x;
    const int jp  = tid >> 3;        // team: columns 2jp, 2jp+1
    const int sub = tid & 7;         // 16-row slice of reduction axis
    const int j0  = jp * 2;
    const int j1  = j0 + 1;
    const int wid = tid >> 6;

    __shared__ __align__(16) float buf[2][CC];  // double-buffered state vector
    __shared__ float wred[8];

    // ---- sequence length (contiguous prefix mask; tid spans T exactly) ----
    const int myM = mask[bb * TT + tid];
    const int len = __syncthreads_count(myM);

    // ---- gold-path score (fwd block only; off the scan critical path) ----
    if (dir == 0) {
        float sc = 0.0f;
        if (myM) {
            const int tg = tags[bb * TT + tid];
            sc += feats[((size_t)(bb * TT + tid)) * CC + tg];
            sc += (tid == 0) ? trans[(CC - 2) * CC + tg]
                             : trans[tags[bb * TT + tid - 1] * CC + tg];
            const int nm = (tid == TT - 1) ? 0 : mask[bb * TT + tid + 1];
            if (!nm) sc += trans[tg * CC + (CC - 1)];
        }
        #pragma unroll
        for (int o = 1; o <= 32; o <<= 1) sc += __shfl_xor(sc, o);
        if ((tid & 63) == 0) wred[wid] = sc;
        __syncthreads();
        if (tid == 0) {
            float s = 0.0f;
            #pragma unroll
            for (int k = 0; k < 8; ++k) s += wred[k];
            atomicAdd(&ws[1], s);
        }
        // wred not reused before the post-loop __syncthreads().
    }

    const int M      = len >> 1;     // fwd steps
    const int nB     = len - M;      // bwd steps (>= 1)
    const int nSteps = dir ? nB : M;

    const float* fb = feats + (size_t)bb * TT * CC;

    // ---- fragments: fwd = E[r][j0/j1] row-pairs; bwd = E[j0/j1][r] col-pairs.
    //      kkA chunk swizzle keeps the wave's 8 16B buf-chunks on 8 bank quads.
    const int s2 = sub >> 1;
    int kkA[4];
    v2f F0v[8], F1v[8];
    #pragma unroll
    for (int k = 0; k < 4; ++k) {
        const int kk = (k + s2) & 3;
        kkA[k] = kk;
        const int r = sub * 16 + kk * 4;
        if (dir == 0) {
            #pragma unroll
            for (int m = 0; m < 2; ++m) {
                const int r0 = r + 2 * m;
                const float2 ta = *(const float2*)&trans[(size_t)(r0    ) * CC + j0];
                const float2 tb = *(const float2*)&trans[(size_t)(r0 + 1) * CC + j0];
                v2f e0, e1;
                e0.x = __expf(ta.x); e0.y = __expf(tb.x);
                e1.x = __expf(ta.y); e1.y = __expf(tb.y);
                F0v[2 * k + m] = e0;
                F1v[2 * k + m] = e1;
            }
        } else {
            const float4 u0 = *(const float4*)&trans[(size_t)j0 * CC + r];
            const float4 u1 = *(const float4*)&trans[(size_t)j1 * CC + r];
            v2f e;
            e.x = __expf(u0.x); e.y = __expf(u0.y); F0v[2 * k]     = e;
            e.x = __expf(u0.z); e.y = __expf(u0.w); F0v[2 * k + 1] = e;
            e.x = __expf(u1.x); e.y = __expf(u1.y); F1v[2 * k]     = e;
            e.x = __expf(u1.z); e.y = __expf(u1.w); F1v[2 * k + 1] = e;
        }
    }

    // ---- init: fwd a_0 = onehot(START);
    //      bwd c_0[j] = exp(trans[j][STOP]) * exp(f_{len-1}[j]) (premultiplied)
    if (tid < CC) {
        if (dir == 0) {
            buf[0][tid] = (tid == CC - 2) ? 1.0f : 0.0f;
        } else {
            buf[0][tid] = __expf(trans[(size_t)tid * CC + (CC - 1)])
                        * __expf(fb[(size_t)(len - 1) * CC + tid]);
        }
    }

    // ---- feats prefetch: fwd walks t up from 0; bwd walks down from len-2 ----
    float2 fx[PF];
    #pragma unroll
    for (int k = 0; k < PF; ++k) {
        int tg;
        if (dir == 0) tg = k;
        else { tg = len - 2 - k; tg = (tg > 0) ? tg : 0; }
        fx[k] = *(const float2*)&fb[(size_t)tg * CC + j0];
    }

    const float* pb0 = &buf[0][sub * 16];
    const float* pb1 = &buf[1][sub * 16];

    float S = 0.0f;                          // sum of applied log(c)
    const int nUp = (nSteps + 3) & ~3;       // may be 0 (fwd with len==1)

    for (int tc = 0; tc < nUp; tc += 4) {
        #pragma unroll
        for (int k = 0; k < 4; ++k) {
            const int it  = tc + k;
            const int par = k & 1;           // == it & 1
            bar_nodrain();                   // buf[par] now visible
            const float4* q = (const float4*)(par ? pb1 : pb0);
            float c = 1.0f;
            if (k == 3) c = buf[1][0];       // current state[0]; broadcast read

            v2f a0 = {0.f, 0.f}, a1 = {0.f, 0.f};
            v2f b0 = {0.f, 0.f}, b1 = {0.f, 0.f};
            #pragma unroll
            for (int kq = 0; kq < 4; ++kq) {
                const float4 P = q[kkA[kq]];
                v2f P01; P01.x = P.x; P01.y = P.y;
                v2f P23; P23.x = P.z; P23.y = P.w;
                a0 = __builtin_elementwise_fma(F0v[2 * kq],     P01, a0);
                a1 = __builtin_elementwise_fma(F0v[2 * kq + 1], P23, a1);
                b0 = __builtin_elementwise_fma(F1v[2 * kq],     P01, b0);
                b1 = __builtin_elementwise_fma(F1v[2 * kq + 1], P23, b1);
            }
            a0 += a1; b0 += b1;
            float s0 = red8(a0.x + a0.y);
            float s1 = red8(b0.x + b0.y);

            // emission factor (exps stay inside step k: keeps the global
            // prefetch a full PF=4 steps ahead of consumption).
            // bwd's LAST step writes the raw matvec (its premultiplier
            // belongs to the fwd side) so the junction counts each feat once.
            const bool noMul = (dir != 0) && (it == nSteps - 1);
            const float m0 = noMul ? 1.0f : __expf(fx[k].x);
            const float m1 = noMul ? 1.0f : __expf(fx[k].y);

            float v0, v1;
            if (k == 3) {
                const float rinv = __builtin_amdgcn_rcpf(c);
                v0 = m0 * s0 * rinv;
                v1 = m1 * s1 * rinv;
            } else {
                v0 = m0 * s0;
                v1 = m1 * s1;
            }

            // prefetch feats for step it+PF (clamped; identical work per call)
            int tn;
            if (dir == 0) { tn = it + PF;           tn = (tn < TT) ? tn : (TT - 1); }
            else          { tn = len - 2 - (it + PF); tn = (tn > 0) ? tn : 0; }
            fx[k] = *(const float2*)&fb[(size_t)tn * CC + j0];

            if (it < nSteps) {               // uniform branch
                if (k == 3) S += __logf(c);  // record exactly what was divided
                if (sub == 0) {
                    float2 w2; w2.x = v0; w2.y = v1;
                    *(float2*)&buf[par ^ 1][j0] = w2;
                }
            }
            // frozen steps: no writes, no S update -> state stays exact.
        }
    }

    // ---- write final vector + log-scale sum to workspace ----
    __syncthreads();                         // init/loop writes visible
    float* resv = ws + 16 + (size_t)bb * WS_STRIDE + dir * 128;
    if (sub == 0) {
        const float2 uu = *(const float2*)&buf[nSteps & 1][j0];
        *(float2*)&resv[j0] = uu;            // 64 teams cover all 128 cols
    }
    if (tid == 0) ws[16 + (size_t)bb * WS_STRIDE + 256 + dir] = S;
}

// Junction: logZ_b = log(sum_i aM[i]*bM[i]) + SF + SB, accumulated into ws[0].
__global__ void crf_join(const float* __restrict__ ws, float* __restrict__ acc)
{
    const int b = blockIdx.x;
    const int i = threadIdx.x;               // 64 threads: 2 cols each
    const float* base = ws + 16 + (size_t)b * WS_STRIDE;
    float z = base[i] * base[128 + i] + base[64 + i] * base[192 + i];
    #pragma unroll
    for (int o = 1; o <= 32; o <<= 1) z += __shfl_xor(z, o);
    if (i == 0) atomicAdd(&acc[0], __logf(z) + base[256] + base[257]);
}

__global__ void crf_final(const float* __restrict__ acc, float* __restrict__ out)
{
    out[0] = (acc[0] - acc[1]) * (1.0f / (float)BB);
}

extern "C" void kernel_launch(void* const* d_in, const int* in_sizes, int n_in,
                              void* d_out, int out_size, void* d_ws, size_t ws_size,
                              hipStream_t stream)
{
    const float* feats = (const float*)d_in[0];
    const int*   mask  = (const int*)d_in[1];
    const int*   tags  = (const int*)d_in[2];
    const float* trans = (const float*)d_in[3];
    float* out = (float*)d_out;
    float* ws  = (float*)d_ws;               // needs ~160 KB

    hipMemsetAsync(ws, 0, 2 * sizeof(float), stream);
    crf_scan<<<BB * 2, NTHR, 0, stream>>>(feats, mask, tags, trans, ws);
    crf_join<<<BB, 64, 0, stream>>>(ws, ws);
    crf_final<<<1, 1, 0, stream>>>(ws, out);
}